// Round 7
// baseline (28.462 us; speedup 1.0000x reference)
//
#include <hip/hip_runtime.h>

constexpr int A_TOTAL = 5456;
constexpr int BATCH = 16;
constexpr int NUM_CLASSES = 80;
constexpr int NUM_CH = NUM_CLASSES + 2;   // 82
constexpr int MAX_OBJ = 32;
constexpr int LEVELS = 5;
constexpr int BINS = MAX_OBJ * LEVELS;    // 160
constexpr int BLK = 256;
constexpr int APB = BLK / 4;                        // 64 anchors per block (QPR=4)
constexpr int NBLK_L = (A_TOTAL + APB - 1) / APB;   // 86 blocks per batch (loss)
constexpr int NBLK_G = (A_TOTAL + BLK - 1) / BLK;   // 22 blocks per batch (gather)

__device__ __forceinline__ int lev_of(int a) {
    return (a < 4096) ? 0 : (a < 5120) ? 1 : (a < 5376) ? 2 : (a < 5440) ? 3 : 4;
}

// Loss kernel: 4 lanes per anchor (each 4-lane cluster's float4/float2 loads
// cover contiguous 64B lines). BLK=256 -> 1376 blocks, ~5.3/CU (balanced),
// __launch_bounds__(256,8) caps VGPR<=64 so 8 blocks (32 waves) are resident.
// LDS histogram -> device-scope atomicAdd into [B][BINS] bins (zeroed by the
// preceding memset); block geometry is decoupled from the gather cost.
__global__ void __launch_bounds__(BLK, 8)
loss_accum_kernel(const float* __restrict__ cls_pred,
                  const float* __restrict__ loc_pred,
                  const float* __restrict__ cls_tar,
                  const float* __restrict__ loc_tar,
                  const int*   __restrict__ ind_tar,
                  float* __restrict__ g_sum,   // [B][BINS]
                  float* __restrict__ g_cnt,   // [B][BINS]
                  float* __restrict__ out) {
    __shared__ float s_sum[BINS];
    __shared__ float s_cnt[BINS];
    const int t = threadIdx.x;
    if (t < BINS) { s_sum[t] = 0.f; s_cnt[t] = 0.f; }
    __syncthreads();

    const int b = blockIdx.y;
    const int a = blockIdx.x * APB + (t >> 2);  // anchor row
    const int q = t & 3;                        // quarter-row id
    const bool valid = a < A_TOTAL;

    float fl = 0.f;
    size_t row = 0;
    if (valid) {
        row = (size_t)b * A_TOTAL + a;
        const float4* pred4 = (const float4*)cls_pred + row * 20 + q;     // classes 16j+4q..+3
        const float2* tar2  = (const float2*)cls_tar  + row * 41 + 2 * q;
        #pragma unroll
        for (int j = 0; j < 5; ++j) {
            float4 p4 = pred4[4 * j];
            float2 ta = tar2[8 * j];
            float2 tb = tar2[8 * j + 1];
            float ps[4] = {p4.x, p4.y, p4.z, p4.w};
            float ts[4] = {ta.x, ta.y, tb.x, tb.y};
            #pragma unroll
            for (int k = 0; k < 4; ++k) {
                float p  = fminf(fmaxf(ps[k], 1e-7f), 1.0f - 1e-7f);
                float tt = ts[k];
                float ce = -(tt * __logf(p) + (1.f - tt) * __logf(1.f - p));
                float alpha_t = tt * 0.25f + (1.f - tt) * 0.75f;
                float pt = tt * (1.f - p) + (1.f - tt) * p;
                fl += alpha_t * pt * pt * ce;
            }
        }
    }
    // reduce quarter-row partials (4-lane clusters are wave-aligned)
    fl += __shfl_xor(fl, 1);
    fl += __shfl_xor(fl, 2);

    if (valid && q == 0) {
        float pos = cls_tar[row * NUM_CH + (NUM_CH - 1)];  // line covered by cluster loads
        out[(size_t)BATCH * A_TOTAL + row] = pos;          // output 1: [B, A]

        float4 T = ((const float4*)(loc_tar  + row * 4))[0];
        float4 P = ((const float4*)(loc_pred + row * 4))[0];
        float area_t = (T.x + T.z) * (T.y + T.w);
        float area_p = (P.x + P.z) * (P.y + P.w);
        float inter  = (fminf(T.x, P.x) + fminf(T.z, P.z)) * (fminf(T.y, P.y) + fminf(T.w, P.w));
        float uni    = area_t + area_p - inter;
        float iou    = inter / fmaxf(uni, 1e-7f);
        float enc    = (fmaxf(T.x, P.x) + fmaxf(T.z, P.z)) * (fmaxf(T.y, P.y) + fmaxf(T.w, P.w));
        float giou   = iou - (enc - uni) / fmaxf(enc, 1e-7f);
        float loss   = fl + (1.f - giou);

        int bin = ind_tar[row] * LEVELS + lev_of(a);
        atomicAdd(&s_sum[bin], loss);
        atomicAdd(&s_cnt[bin], 1.0f);
    }
    __syncthreads();
    // flush: at most APB(=64) nonzero bins per block
    if (t < BINS) {
        float c = s_cnt[t];
        if (c != 0.f) {
            atomicAdd(&g_sum[b * BINS + t], s_sum[t]);
            atomicAdd(&g_cnt[b * BINS + t], c);
        }
    }
}

// Gather kernel: direct bin read (no reduce loop) -> per-object target ->
// scatter to anchors; pos staged in d_out by the loss kernel.
__global__ void __launch_bounds__(BLK)
gather_kernel(const float* __restrict__ g_sum,
              const float* __restrict__ g_cnt,
              const int*   __restrict__ ind_tar,
              const int*   __restrict__ bbox_cnt,
              float* __restrict__ out) {
    __shared__ float s_mean[BINS];
    __shared__ float s_tgt[BINS];
    const int t = threadIdx.x;
    const int b = blockIdx.y;

    if (t < BINS) {
        float s = g_sum[b * BINS + t];
        float c = g_cnt[b * BINS + t];
        s_mean[t] = s / fmaxf(1.0f, c);
    }
    __syncthreads();

    if (t < MAX_OBJ) {
        float mean[LEVELS];
        float mx = -1e30f;
        #pragma unroll
        for (int l = 0; l < LEVELS; ++l) {
            mean[l] = s_mean[t * LEVELS + l];
            mx = fmaxf(mx, mean[l]);
        }
        float lmax = mx + 1e-5f;
        float mn = 1e30f;
        #pragma unroll
        for (int l = 0; l < LEVELS; ++l) {
            if (mean[l] == 0.0f) mean[l] = lmax;
            mn = fminf(mn, mean[l]);
        }
        float denom = lmax - mn;
        float tgt[LEVELS];
        float m1 = -1e30f, m2 = -1e30f, m3 = -1e30f;
        #pragma unroll
        for (int l = 0; l < LEVELS; ++l) {
            float v = 1.0f - (mean[l] - mn) / denom;
            tgt[l] = v;
            if (v > m1)      { m3 = m2; m2 = m1; m1 = v; }
            else if (v > m2) { m3 = m2; m2 = v; }
            else if (v > m3) { m3 = v; }
        }
        const bool valid = t < bbox_cnt[b];
        #pragma unroll
        for (int l = 0; l < LEVELS; ++l) {
            float v = tgt[l];
            v = (v >= m3) ? v : 0.0f;
            s_tgt[t * LEVELS + l] = valid ? v : 0.0f;
        }
    }
    __syncthreads();

    const int a = blockIdx.x * BLK + t;
    if (a >= A_TOTAL) return;
    const size_t row = (size_t)b * A_TOTAL + a;
    float pos = out[(size_t)BATCH * A_TOTAL + row];  // staged by loss kernel (dense)
    int o = ind_tar[row];
    out[row] = (pos > 0.0f) ? s_tgt[o * LEVELS + lev_of(a)] : 1.0f;
}

extern "C" void kernel_launch(void* const* d_in, const int* in_sizes, int n_in,
                              void* d_out, int out_size, void* d_ws, size_t ws_size,
                              hipStream_t stream) {
    const float* cls_pred = (const float*)d_in[0];
    const float* loc_pred = (const float*)d_in[1];
    const float* cls_tar  = (const float*)d_in[2];
    const float* loc_tar  = (const float*)d_in[3];
    const int*   ind_tar  = (const int*)d_in[4];
    const int*   bbox_cnt = (const int*)d_in[5];
    float* out = (float*)d_out;

    float* g_sum = (float*)d_ws;                  // [16][160]
    float* g_cnt = g_sum + (size_t)BATCH * BINS;  // [16][160]

    hipMemsetAsync(d_ws, 0, 2 * BATCH * BINS * sizeof(float), stream);

    loss_accum_kernel<<<dim3(NBLK_L, BATCH), dim3(BLK), 0, stream>>>(
        cls_pred, loc_pred, cls_tar, loc_tar, ind_tar, g_sum, g_cnt, out);
    gather_kernel<<<dim3(NBLK_G, BATCH), dim3(BLK), 0, stream>>>(
        g_sum, g_cnt, ind_tar, bbox_cnt, out);
}

// Round 8
// 27.816 us; speedup vs baseline: 1.0232x; 1.0232x over previous
//
#include <hip/hip_runtime.h>

constexpr int A_TOTAL = 5456;
constexpr int BATCH = 16;
constexpr int NUM_CLASSES = 80;
constexpr int NUM_CH = NUM_CLASSES + 2;   // 82
constexpr int MAX_OBJ = 32;
constexpr int LEVELS = 5;
constexpr int BINS = MAX_OBJ * LEVELS;    // 160
constexpr int BLK_L = 512;                          // loss block: 8 waves
constexpr int APB = BLK_L / 4;                      // 128 anchors per block (QPR=4)
constexpr int NBLK = (A_TOTAL + APB - 1) / APB;     // 43 blocks per batch
constexpr int BLK_G = 256;                          // gather block

__device__ __forceinline__ int lev_of(int a) {
    return (a < 4096) ? 0 : (a < 5120) ? 1 : (a < 5376) ? 2 : (a < 5440) ? 3 : 4;
}

// Loss kernel: QPR=4 lanes per anchor (4-lane cluster = one 64B line per
// float4 load), BLK=512 -> grid 688 blocks = 2.69/CU (tail 1.12 vs R6's
// 1.45). Per-block partial histograms, unconditional writes (no init, no
// global atomics) -- R6-proven scheme, only the geometry changes.
__global__ void __launch_bounds__(BLK_L)
loss_accum_kernel(const float* __restrict__ cls_pred,
                  const float* __restrict__ loc_pred,
                  const float* __restrict__ cls_tar,
                  const float* __restrict__ loc_tar,
                  const int*   __restrict__ ind_tar,
                  float* __restrict__ p_sum,   // [B][NBLK][BINS]
                  float* __restrict__ p_cnt,   // [B][NBLK][BINS]
                  float* __restrict__ out) {
    __shared__ float s_sum[BINS];
    __shared__ float s_cnt[BINS];
    const int t = threadIdx.x;
    if (t < BINS) { s_sum[t] = 0.f; s_cnt[t] = 0.f; }
    __syncthreads();

    const int b = blockIdx.y;
    const int a = blockIdx.x * APB + (t >> 2);  // anchor row
    const int q = t & 3;                        // quarter-row id
    const bool valid = a < A_TOTAL;

    float fl = 0.f;
    size_t row = 0;
    if (valid) {
        row = (size_t)b * A_TOTAL + a;
        const float4* pred4 = (const float4*)cls_pred + row * 20 + q;     // classes 16j+4q..+3
        const float2* tar2  = (const float2*)cls_tar  + row * 41 + 2 * q;
        #pragma unroll
        for (int j = 0; j < 5; ++j) {
            float4 p4 = pred4[4 * j];
            float2 ta = tar2[8 * j];
            float2 tb = tar2[8 * j + 1];
            float ps[4] = {p4.x, p4.y, p4.z, p4.w};
            float ts[4] = {ta.x, ta.y, tb.x, tb.y};
            #pragma unroll
            for (int k = 0; k < 4; ++k) {
                float p  = fminf(fmaxf(ps[k], 1e-7f), 1.0f - 1e-7f);
                float tt = ts[k];
                float ce = -(tt * __logf(p) + (1.f - tt) * __logf(1.f - p));
                float alpha_t = tt * 0.25f + (1.f - tt) * 0.75f;
                float pt = tt * (1.f - p) + (1.f - tt) * p;
                fl += alpha_t * pt * pt * ce;
            }
        }
    }
    // reduce quarter-row partials (4-lane clusters are wave-aligned)
    fl += __shfl_xor(fl, 1);
    fl += __shfl_xor(fl, 2);

    if (valid && q == 0) {
        float pos = cls_tar[row * NUM_CH + (NUM_CH - 1)];  // line covered by cluster loads
        out[(size_t)BATCH * A_TOTAL + row] = pos;          // output 1: [B, A]

        float4 T = ((const float4*)(loc_tar  + row * 4))[0];
        float4 P = ((const float4*)(loc_pred + row * 4))[0];
        float area_t = (T.x + T.z) * (T.y + T.w);
        float area_p = (P.x + P.z) * (P.y + P.w);
        float inter  = (fminf(T.x, P.x) + fminf(T.z, P.z)) * (fminf(T.y, P.y) + fminf(T.w, P.w));
        float uni    = area_t + area_p - inter;
        float iou    = inter / fmaxf(uni, 1e-7f);
        float enc    = (fmaxf(T.x, P.x) + fmaxf(T.z, P.z)) * (fmaxf(T.y, P.y) + fmaxf(T.w, P.w));
        float giou   = iou - (enc - uni) / fmaxf(enc, 1e-7f);
        float loss   = fl + (1.f - giou);

        int bin = ind_tar[row] * LEVELS + lev_of(a);
        atomicAdd(&s_sum[bin], loss);
        atomicAdd(&s_cnt[bin], 1.0f);
    }
    __syncthreads();
    const size_t slot = ((size_t)b * NBLK + blockIdx.x) * BINS;
    if (t < BINS) {
        p_sum[slot + t] = s_sum[t];
        p_cnt[slot + t] = s_cnt[t];
    }
}

// Gather kernel (R2/R6-proven): reduce partials (L2-hot) -> per-(o,l) target
// -> scatter to anchors; pos staged in d_out by the loss kernel.
__global__ void __launch_bounds__(BLK_G)
gather_kernel(const float* __restrict__ p_sum,
              const float* __restrict__ p_cnt,
              const int*   __restrict__ ind_tar,
              const int*   __restrict__ bbox_cnt,
              float* __restrict__ out) {
    __shared__ float s_mean[BINS];
    __shared__ float s_tgt[BINS];
    const int t = threadIdx.x;
    const int b = blockIdx.y;

    if (t < BINS) {
        float s = 0.f, c = 0.f;
        const size_t base = (size_t)b * NBLK * BINS + t;
        #pragma unroll 4
        for (int k = 0; k < NBLK; ++k) {
            s += p_sum[base + (size_t)k * BINS];
            c += p_cnt[base + (size_t)k * BINS];
        }
        s_mean[t] = s / fmaxf(1.0f, c);
    }
    __syncthreads();

    if (t < MAX_OBJ) {
        float mean[LEVELS];
        float mx = -1e30f;
        #pragma unroll
        for (int l = 0; l < LEVELS; ++l) {
            mean[l] = s_mean[t * LEVELS + l];
            mx = fmaxf(mx, mean[l]);
        }
        float lmax = mx + 1e-5f;
        float mn = 1e30f;
        #pragma unroll
        for (int l = 0; l < LEVELS; ++l) {
            if (mean[l] == 0.0f) mean[l] = lmax;
            mn = fminf(mn, mean[l]);
        }
        float denom = lmax - mn;
        float tgt[LEVELS];
        float m1 = -1e30f, m2 = -1e30f, m3 = -1e30f;
        #pragma unroll
        for (int l = 0; l < LEVELS; ++l) {
            float v = 1.0f - (mean[l] - mn) / denom;
            tgt[l] = v;
            if (v > m1)      { m3 = m2; m2 = m1; m1 = v; }
            else if (v > m2) { m3 = m2; m2 = v; }
            else if (v > m3) { m3 = v; }
        }
        const bool valid = t < bbox_cnt[b];
        #pragma unroll
        for (int l = 0; l < LEVELS; ++l) {
            float v = tgt[l];
            v = (v >= m3) ? v : 0.0f;
            s_tgt[t * LEVELS + l] = valid ? v : 0.0f;
        }
    }
    __syncthreads();

    const int a = blockIdx.x * BLK_G + t;
    if (a >= A_TOTAL) return;
    const size_t row = (size_t)b * A_TOTAL + a;
    float pos = out[(size_t)BATCH * A_TOTAL + row];  // staged by loss kernel (dense)
    int o = ind_tar[row];
    out[row] = (pos > 0.0f) ? s_tgt[o * LEVELS + lev_of(a)] : 1.0f;
}

extern "C" void kernel_launch(void* const* d_in, const int* in_sizes, int n_in,
                              void* d_out, int out_size, void* d_ws, size_t ws_size,
                              hipStream_t stream) {
    const float* cls_pred = (const float*)d_in[0];
    const float* loc_pred = (const float*)d_in[1];
    const float* cls_tar  = (const float*)d_in[2];
    const float* loc_tar  = (const float*)d_in[3];
    const int*   ind_tar  = (const int*)d_in[4];
    const int*   bbox_cnt = (const int*)d_in[5];
    float* out = (float*)d_out;

    float* p_sum = (float*)d_ws;                       // [16][43][160]
    float* p_cnt = p_sum + (size_t)BATCH * NBLK * BINS;

    loss_accum_kernel<<<dim3(NBLK, BATCH), dim3(BLK_L), 0, stream>>>(
        cls_pred, loc_pred, cls_tar, loc_tar, ind_tar, p_sum, p_cnt, out);
    gather_kernel<<<dim3((A_TOTAL + BLK_G - 1) / BLK_G, BATCH), dim3(BLK_G), 0, stream>>>(
        p_sum, p_cnt, ind_tar, bbox_cnt, out);
}